// Round 10
// baseline (81.150 us; speedup 1.0000x reference)
//
#include <hip/hip_runtime.h>
#include <math.h>

// DGP loss — ROUND 10: fence-free single-kernel fusion.
// R8 fused regression root-caused to per-block __threadfence (device-scope
// fence = per-XCD L2 writeback storm on CDNA4), NOT fusion. This version:
//   - one atomicAdd(double) into a single global accumulator (device-scope
//     coherent by default; poison 0xAA..AA as double = -2e-103, numerically
//     invisible vs the ~7e-6 sum -> no init needed),
//   - ordering WITHOUT a fence: branch on the returned old value (data
//     dependence forces s_waitcnt on the atomic ack) before the ticket atomic,
//   - ticket "last block" accepts init in {0, 0xAAAAAAAA} (validated in R8),
//   - last block reads the accumulator with atomicAdd(+0.0) and stores out.
// Staging keeps R9's max-MLP structure (all ~46 global loads issued before
// any rne/ds_write — R8 counters showed the fused loop serialized at
// vmcnt(0)/iter, 625 GB/s; R9's fix bought ~8us).
//
// Semantics locked (bit-exact R5-R9, absmax 0.0): bf16-RNE-round input reads,
// np fp32 chain (IEEE div/sqrt, numpy 8-acc pairwise channel sum with
// contract(off)), CR fp32 expm1 via fp64, cnt==2, double accumulate, /3534400.
// fma screen (err <=7e-5 at sq~18 vs 1e-3 margin) keeps the exact chain cold.

#define HP    188
#define IMW   192
#define NCH   32
#define TW    64
#define HWC   68          // 64 + 4 halo cols
#define NR    5           // 1 output row + 4 halo rows
#define PLANE (IMW * IMW)
#define NBLK  (3 * HP * 2)   // 1128 blocks
#define NSLOT (8 * NR * HWC) // 2720 float4 staging slots
#define SPT   11             // ceil(2720/256) slots per thread

__device__ __forceinline__ float bf16_rne(float f) {
    unsigned u = __float_as_uint(f);
    u += 0x7fffu + ((u >> 16) & 1u);   // round-to-nearest-even to bf16 grid
    u &= 0xffff0000u;
    return __uint_as_float(u);
}

__global__ __launch_bounds__(256) void dgp_one(
    const float* __restrict__ S,   // [2,32,192,192] bf16-grid values in f32
    const float* __restrict__ D,   // [2,1,192,192]
    double* __restrict__ gacc,     // 1 double in d_ws (poison ok: -2e-103)
    unsigned int* __restrict__ ticket,  // 1 word in d_ws (init 0 or 0xAAAAAAAA)
    float* __restrict__ out)
{
    __shared__ __align__(16) float sm[8][NR][HWC][4];  // 43520 B quad-interleave
    __shared__ float  rd[NR][HWC];
    __shared__ double wsum[4];
    __shared__ int    slast;

    const int tid = threadIdx.x;
    const int tx  = tid & 63;
    const int tg  = tid >> 6;
    const int ox0 = blockIdx.x * TW;
    const int oy  = blockIdx.y;      // patch row (0..187)
    const int b   = blockIdx.z;

    // ---------- phase 1: issue ALL staging loads (max MLP) ----------
    float dv[2];
#pragma unroll
    for (int s = 0; s < 2; ++s) {
        const int t = tid + 256 * s;
        float d = 1.0f;
        if (t < NR * HWC) {
            const int i   = t / HWC;
            const int col = t - i * HWC;
            const int gc  = ox0 + col;
            if (gc < IMW) d = D[(b * IMW + (oy + i)) * IMW + gc];
        }
        dv[s] = d;
    }
    float4 sv[SPT];
#pragma unroll
    for (int s = 0; s < SPT; ++s) {
        const int t = tid + 256 * s;
        float4 v = make_float4(0.f, 0.f, 0.f, 0.f);
        if (t < NSLOT) {
            const int q   = t / (NR * HWC);
            const int rem = t - q * (NR * HWC);
            const int i   = rem / HWC;
            const int col = rem - i * HWC;
            const int gc  = ox0 + col;
            if (gc < IMW) {
                const int base = ((b * NCH + 4 * q) * IMW + (oy + i)) * IMW + gc;
                v.x = S[base];
                v.y = S[base + PLANE];
                v.z = S[base + 2 * PLANE];
                v.w = S[base + 3 * PLANE];
            }
        }
        sv[s] = v;
    }

    // ---------- phase 2: convert + LDS write ----------
#pragma unroll
    for (int s = 0; s < 2; ++s) {
        const int t = tid + 256 * s;
        if (t < NR * HWC) {
            const int i   = t / HWC;
            const int col = t - i * HWC;
            rd[i][col] = 1.0f / (bf16_rne(dv[s]) + 1e-6f);
        }
    }
#pragma unroll
    for (int s = 0; s < SPT; ++s) {
        const int t = tid + 256 * s;
        if (t < NSLOT) {
            const int q   = t / (NR * HWC);
            const int rem = t - q * (NR * HWC);
            const int i   = rem / HWC;
            const int col = rem - i * HWC;
            float4 v = sv[s];
            v.x = bf16_rne(v.x);
            v.y = bf16_rne(v.y);
            v.z = bf16_rne(v.z);
            v.w = bf16_rne(v.w);
            *(float4*)&sm[q][i][col][0] = v;
        }
    }
    __syncthreads();

    // ---------- compute: 64 positions x 4 tap-groups (6 taps each) ----------
    double acc = 0.0;
    const int ox = ox0 + tx;
    if (ox < HP) {
        float cs[NCH];
#pragma unroll
        for (int q = 0; q < 8; ++q) {
            const float4 c4 = *(const float4*)&sm[q][2][tx + 2][0];
            cs[4 * q + 0] = c4.x;
            cs[4 * q + 1] = c4.y;
            cs[4 * q + 2] = c4.z;
            cs[4 * q + 3] = c4.w;
        }
        const float rc = rd[2][tx + 2];

        for (int k = 0; k < 6; ++k) {
            int t = tg * 6 + k;
            t += (t >= 12);                 // skip center tap (i=2,j=2)
            const int i = t / 5;
            const int j = t - 5 * i;

            // HOT: fma screen (conservative; abs err <=7e-5 vs 1e-3 margin)
            float f0 = 0.f, f1 = 0.f, f2 = 0.f, f3 = 0.f;
#pragma unroll
            for (int q = 0; q < 8; ++q) {
                const float4 x = *(const float4*)&sm[q][i][tx + j][0];
                const float t0 = cs[4 * q + 0] - x.x;
                const float t1 = cs[4 * q + 1] - x.y;
                const float t2 = cs[4 * q + 2] - x.z;
                const float t3 = cs[4 * q + 3] - x.w;
                f0 = fmaf(t0, t0, f0);
                f1 = fmaf(t1, t1, f1);
                f2 = fmaf(t2, t2, f2);
                f3 = fmaf(t3, t3, f3);
            }
            const float sq_fast = (f0 + f1) + (f2 + f3);

            if (sq_fast <= 18.001f) {
                // COLD (P~3e-5): exact numpy chain, verbatim R5
                const float rn = rd[i][tx + j];
                const float dd = fabsf(rc - rn);

                float r[8];
                {
#pragma clang fp contract(off)
#pragma unroll
                    for (int blk = 0; blk < 4; ++blk) {
                        const float4 e = *(const float4*)&sm[2 * blk][i][tx + j][0];
                        const float4 o = *(const float4*)&sm[2 * blk + 1][i][tx + j][0];
                        float p;
                        p = cs[8 * blk + 0] - e.x; p = p * p; r[0] = blk ? r[0] + p : p;
                        p = cs[8 * blk + 1] - e.y; p = p * p; r[1] = blk ? r[1] + p : p;
                        p = cs[8 * blk + 2] - e.z; p = p * p; r[2] = blk ? r[2] + p : p;
                        p = cs[8 * blk + 3] - e.w; p = p * p; r[3] = blk ? r[3] + p : p;
                        p = cs[8 * blk + 4] - o.x; p = p * p; r[4] = blk ? r[4] + p : p;
                        p = cs[8 * blk + 5] - o.y; p = p * p; r[5] = blk ? r[5] + p : p;
                        p = cs[8 * blk + 6] - o.z; p = p * p; r[6] = blk ? r[6] + p : p;
                        p = cs[8 * blk + 7] - o.w; p = p * p; r[7] = blk ? r[7] + p : p;
                    }
                }
                const float sq = ((r[0] + r[1]) + (r[2] + r[3]))
                               + ((r[4] + r[5]) + (r[6] + r[7]));

                const float sd  = sqrtf(sq);
                const float ddc = fmaxf(dd, 1e-8f);
                const float sdc = fmaxf(sd, 1e-8f);

                if (ddc > 1e-8f && sdc > 1e-8f) {
                    const float s2 = sdc * sdc;
                    if (s2 <= 18.0f) {                  // else l_sem == 0 exactly
                        const float ls = (float)expm1(-(double)s2) + 1.0f;
                        const float ad = -(ddc / 10.0f);
                        const float ld = (float)expm1((double)ad) + 1.0f;
                        acc += 2.0 * (double)(ld * ls); // cnt == 2
                    }
                }
            }
        }
    }

    // ---------- block reduce ----------
#pragma unroll
    for (int off = 32; off > 0; off >>= 1)
        acc += __shfl_down(acc, off);
    if ((tid & 63) == 0) wsum[tid >> 6] = acc;
    __syncthreads();

    // ---------- fence-free grid reduce ----------
    if (tid == 0) {
        const double part = wsum[0] + wsum[1] + wsum[2] + wsum[3];
        const double oldv = atomicAdd(gacc, part);   // device-scope coherent
        unsigned int old = 0u;
        // data-dependence on oldv forces the atomic ack (s_waitcnt) BEFORE the
        // ticket atomic issues -> release ordering without __threadfence.
        if (__double_as_longlong(oldv) != 0x7ff8000000000001LL)  // always true
            old = atomicAdd(ticket, 1u);
        // last iff old == init + NBLK-1, init in {0, 0xAAAAAAAA} (R8-validated;
        // ranges disjoint).
        slast = (old == (unsigned)(NBLK - 1)) ||
                (old == 0xAAAAAAAAu + (unsigned)(NBLK - 1));
    }
    __syncthreads();

    if (slast && tid == 0) {
        // all 1128 adds (incl. ours) completed before the last ticket ack.
        const double tot = atomicAdd(gacc, 0.0);     // coherent read
        // poison init (-2e-103) is below 1 ulp of the ~7e-6 sum: no correction.
        out[0] = (float)(tot / 3534400.0);           // 1/(B*B*K*K*P)
    }
}

extern "C" void kernel_launch(void* const* d_in, const int* in_sizes, int n_in,
                              void* d_out, int out_size, void* d_ws, size_t ws_size,
                              hipStream_t stream)
{
    const float* S = (const float*)d_in[0];
    const float* D = (const float*)d_in[1];
    if (n_in >= 2 && in_sizes[0] < in_sizes[1]) {
        S = (const float*)d_in[1];
        D = (const float*)d_in[0];
    }
    double*       gacc   = (double*)d_ws;
    unsigned int* ticket = (unsigned int*)((char*)d_ws + 4096);

    dim3 grid(3, HP, 2);   // 1128 blocks
    dgp_one<<<grid, 256, 0, stream>>>(S, D, gacc, ticket, (float*)d_out);
}

// Round 11
// 73.918 us; speedup vs baseline: 1.0978x; 1.0978x over previous
//
#include <hip/hip_runtime.h>
#include <math.h>

// DGP loss — ROUND 11: R9 structure (best, 76.7us) + XCD-aware block swizzle.
// R10 post-mortem: single-address atomicAdd(double)+ticket serializes 1128
// block retirements at one L2 home (~10-19us tail) -> reverted to plain
// per-block partial stores + tiny fin kernel.
// NEW: 1D grid, XCD = linear_id & 7 (round-robin heuristic); each XCD gets a
// CONTIGUOUS run of oy within one (b, x-tile) column, so y-adjacent tiles
// (which share 4 of 5 staged halo rows) resolve their halo in the same
// per-XCD L2 instead of re-fetching HBM. Expect FETCH 28MB -> ~12MB.
//
// Semantics locked (bit-exact R5-R10, absmax 0.0): bf16-RNE-round input
// reads, np fp32 chain (IEEE div/sqrt, numpy 8-acc pairwise channel sum with
// contract(off)), CR fp32 expm1 via fp64, cnt==2, double acc, /3534400.
// fma screen (err <=7e-5 at sq~18 vs 1e-3 margin) keeps the exact chain cold.

#define HP    188
#define IMW   192
#define NCH   32
#define TW    64
#define HWC   68          // 64 + 4 halo cols
#define NR    5           // 1 output row + 4 halo rows
#define PLANE (IMW * IMW)
#define NBLK  (3 * HP * 2)   // 1128 = 141 * 8
#define NSLOT (8 * NR * HWC) // 2720 float4 staging slots
#define SPT   11             // ceil(2720/256) slots per thread

__device__ __forceinline__ float bf16_rne(float f) {
    unsigned u = __float_as_uint(f);
    u += 0x7fffu + ((u >> 16) & 1u);   // round-to-nearest-even to bf16 grid
    u &= 0xffff0000u;
    return __uint_as_float(u);
}

__global__ __launch_bounds__(256) void dgp_tiled(
    const float* __restrict__ S,   // [2,32,192,192] bf16-grid values in f32
    const float* __restrict__ D,   // [2,1,192,192]
    double* __restrict__ partials) // [NBLK] plain stores
{
    __shared__ __align__(16) float sm[8][NR][HWC][4];  // 43520 B quad-interleave
    __shared__ float  rd[NR][HWC];
    __shared__ double wsum[4];

    const int tid = threadIdx.x;
    const int tx  = tid & 63;
    const int tg  = tid >> 6;

    // ---- XCD-aware tile decode: XCD (l&7) owns a contiguous oy-run ----
    const int l   = blockIdx.x;          // 0..1127, dispatched ~in order
    const int xcd = l & 7;               // assumed XCD assignment (heuristic)
    const int g   = xcd * 141 + (l >> 3);// contiguous tile range per XCD
    const int c   = g / HP;              // column 0..5 = (b, xtile)
    const int oy  = g - c * HP;          // 0..187, contiguous within column
    const int b   = c / 3;
    const int ox0 = (c - 3 * b) * TW;

    // ---------- phase 1: issue ALL staging loads (max MLP) ----------
    float dv[2];
#pragma unroll
    for (int s = 0; s < 2; ++s) {
        const int t = tid + 256 * s;
        float d = 1.0f;
        if (t < NR * HWC) {
            const int i   = t / HWC;
            const int col = t - i * HWC;
            const int gc  = ox0 + col;
            if (gc < IMW) d = D[(b * IMW + (oy + i)) * IMW + gc];
        }
        dv[s] = d;
    }
    float4 sv[SPT];
#pragma unroll
    for (int s = 0; s < SPT; ++s) {
        const int t = tid + 256 * s;
        float4 v = make_float4(0.f, 0.f, 0.f, 0.f);
        if (t < NSLOT) {
            const int q   = t / (NR * HWC);
            const int rem = t - q * (NR * HWC);
            const int i   = rem / HWC;
            const int col = rem - i * HWC;
            const int gc  = ox0 + col;
            if (gc < IMW) {
                const int base = ((b * NCH + 4 * q) * IMW + (oy + i)) * IMW + gc;
                v.x = S[base];
                v.y = S[base + PLANE];
                v.z = S[base + 2 * PLANE];
                v.w = S[base + 3 * PLANE];
            }
        }
        sv[s] = v;
    }

    // ---------- phase 2: convert + LDS write ----------
#pragma unroll
    for (int s = 0; s < 2; ++s) {
        const int t = tid + 256 * s;
        if (t < NR * HWC) {
            const int i   = t / HWC;
            const int col = t - i * HWC;
            rd[i][col] = 1.0f / (bf16_rne(dv[s]) + 1e-6f);
        }
    }
#pragma unroll
    for (int s = 0; s < SPT; ++s) {
        const int t = tid + 256 * s;
        if (t < NSLOT) {
            const int q   = t / (NR * HWC);
            const int rem = t - q * (NR * HWC);
            const int i   = rem / HWC;
            const int col = rem - i * HWC;
            float4 v = sv[s];
            v.x = bf16_rne(v.x);
            v.y = bf16_rne(v.y);
            v.z = bf16_rne(v.z);
            v.w = bf16_rne(v.w);
            *(float4*)&sm[q][i][col][0] = v;
        }
    }
    __syncthreads();

    // ---------- compute: 64 positions x 4 tap-groups (6 taps each) ----------
    double acc = 0.0;
    const int ox = ox0 + tx;
    if (ox < HP) {
        float cs[NCH];
#pragma unroll
        for (int q = 0; q < 8; ++q) {
            const float4 c4 = *(const float4*)&sm[q][2][tx + 2][0];
            cs[4 * q + 0] = c4.x;
            cs[4 * q + 1] = c4.y;
            cs[4 * q + 2] = c4.z;
            cs[4 * q + 3] = c4.w;
        }
        const float rc = rd[2][tx + 2];

        for (int k = 0; k < 6; ++k) {
            int t = tg * 6 + k;
            t += (t >= 12);                 // skip center tap (i=2,j=2)
            const int i = t / 5;
            const int j = t - 5 * i;

            // HOT: fma screen (conservative; abs err <=7e-5 vs 1e-3 margin)
            float f0 = 0.f, f1 = 0.f, f2 = 0.f, f3 = 0.f;
#pragma unroll
            for (int q = 0; q < 8; ++q) {
                const float4 x = *(const float4*)&sm[q][i][tx + j][0];
                const float t0 = cs[4 * q + 0] - x.x;
                const float t1 = cs[4 * q + 1] - x.y;
                const float t2 = cs[4 * q + 2] - x.z;
                const float t3 = cs[4 * q + 3] - x.w;
                f0 = fmaf(t0, t0, f0);
                f1 = fmaf(t1, t1, f1);
                f2 = fmaf(t2, t2, f2);
                f3 = fmaf(t3, t3, f3);
            }
            const float sq_fast = (f0 + f1) + (f2 + f3);

            if (sq_fast <= 18.001f) {
                // COLD (P~3e-5): exact numpy chain, verbatim R5
                const float rn = rd[i][tx + j];
                const float dd = fabsf(rc - rn);

                float r[8];
                {
#pragma clang fp contract(off)
#pragma unroll
                    for (int blk = 0; blk < 4; ++blk) {
                        const float4 e = *(const float4*)&sm[2 * blk][i][tx + j][0];
                        const float4 o = *(const float4*)&sm[2 * blk + 1][i][tx + j][0];
                        float p;
                        p = cs[8 * blk + 0] - e.x; p = p * p; r[0] = blk ? r[0] + p : p;
                        p = cs[8 * blk + 1] - e.y; p = p * p; r[1] = blk ? r[1] + p : p;
                        p = cs[8 * blk + 2] - e.z; p = p * p; r[2] = blk ? r[2] + p : p;
                        p = cs[8 * blk + 3] - e.w; p = p * p; r[3] = blk ? r[3] + p : p;
                        p = cs[8 * blk + 4] - o.x; p = p * p; r[4] = blk ? r[4] + p : p;
                        p = cs[8 * blk + 5] - o.y; p = p * p; r[5] = blk ? r[5] + p : p;
                        p = cs[8 * blk + 6] - o.z; p = p * p; r[6] = blk ? r[6] + p : p;
                        p = cs[8 * blk + 7] - o.w; p = p * p; r[7] = blk ? r[7] + p : p;
                    }
                }
                const float sq = ((r[0] + r[1]) + (r[2] + r[3]))
                               + ((r[4] + r[5]) + (r[6] + r[7]));

                const float sd  = sqrtf(sq);
                const float ddc = fmaxf(dd, 1e-8f);
                const float sdc = fmaxf(sd, 1e-8f);

                if (ddc > 1e-8f && sdc > 1e-8f) {
                    const float s2 = sdc * sdc;
                    if (s2 <= 18.0f) {                  // else l_sem == 0 exactly
                        const float ls = (float)expm1(-(double)s2) + 1.0f;
                        const float ad = -(ddc / 10.0f);
                        const float ld = (float)expm1((double)ad) + 1.0f;
                        acc += 2.0 * (double)(ld * ls); // cnt == 2
                    }
                }
            }
        }
    }

    // block reduce (double) + ONE plain store per block
#pragma unroll
    for (int off = 32; off > 0; off >>= 1)
        acc += __shfl_down(acc, off);
    if ((tid & 63) == 0) wsum[tid >> 6] = acc;
    __syncthreads();
    if (tid == 0)
        partials[l] = wsum[0] + wsum[1] + wsum[2] + wsum[3];
}

__global__ __launch_bounds__(256) void dgp_fin(
    const double* __restrict__ partials, float* __restrict__ out)
{
    const int tid = threadIdx.x;
    double acc = 0.0;
    for (int k = tid; k < NBLK; k += 256)
        acc += partials[k];
#pragma unroll
    for (int off = 32; off > 0; off >>= 1)
        acc += __shfl_down(acc, off);
    __shared__ double ws[4];
    if ((tid & 63) == 0) ws[tid >> 6] = acc;
    __syncthreads();
    if (tid == 0)
        out[0] = (float)((ws[0] + ws[1] + ws[2] + ws[3]) / 3534400.0);
}

extern "C" void kernel_launch(void* const* d_in, const int* in_sizes, int n_in,
                              void* d_out, int out_size, void* d_ws, size_t ws_size,
                              hipStream_t stream)
{
    const float* S = (const float*)d_in[0];
    const float* D = (const float*)d_in[1];
    if (n_in >= 2 && in_sizes[0] < in_sizes[1]) {
        S = (const float*)d_in[1];
        D = (const float*)d_in[0];
    }
    double* partials = (double*)d_ws;   // 1128 * 8 B, every slot written

    dgp_tiled<<<NBLK, 256, 0, stream>>>(S, D, partials);
    dgp_fin<<<1, 256, 0, stream>>>(partials, (float*)d_out);
}